// Round 12
// baseline (2939.625 us; speedup 1.0000x reference)
//
#include <hip/hip_runtime.h>

typedef __attribute__((ext_vector_type(8))) short short8;
typedef __attribute__((ext_vector_type(4))) float f32x4;
typedef __attribute__((ext_vector_type(4))) unsigned short us4;

#define MFMA_BF16(a,b,c) __builtin_amdgcn_mfma_f32_16x16x32_bf16((a),(b),(c),0,0,0)

__device__ __forceinline__ unsigned short f2bf(float f) {
  unsigned int u = __float_as_uint(f);
  u += 0x7fffu + ((u >> 16) & 1u);   // round-to-nearest-even
  return (unsigned short)(u >> 16);
}

// pack two f32 -> two bf16 in one instruction (lo -> bits[15:0], hi -> bits[31:16])
__device__ __forceinline__ unsigned cvt_pk_bf16(float lo, float hi) {
  unsigned r;
  asm("v_cvt_pk_bf16_f32 %0, %1, %2" : "=v"(r) : "v"(lo), "v"(hi));
  return r;
}

// bijective XCD-chunk swizzle (attention only)
__device__ __forceinline__ int xcd_swz(int lid, int nwg) {
  return (lid & 7) * (nwg >> 3) + (lid >> 3);
}

// ---------- weight transpose + f32->bf16: src f32 [R][C] -> dst bf16 [C][R], batched over z ----------
__global__ __launch_bounds__(256) void wtrans_kernel(const float* __restrict__ src,
                                                     unsigned short* __restrict__ dst,
                                                     int R, int C) {
  __shared__ float tile[32][33];
  int c0 = blockIdx.x * 32, r0 = blockIdx.y * 32;
  const float* s = src + (size_t)blockIdx.z * R * C;
  unsigned short* d = dst + (size_t)blockIdx.z * R * C;
  int tx = threadIdx.x, ty = threadIdx.y;
#pragma unroll
  for (int i = 0; i < 32; i += 8)
    tile[ty + i][tx] = s[(size_t)(r0 + ty + i) * C + c0 + tx];
  __syncthreads();
#pragma unroll
  for (int i = 0; i < 32; i += 8)
    d[(size_t)(c0 + ty + i) * R + r0 + tx] = f2bf(tile[tx][ty + i]);
}

// ---------- embed: h = x @ W_in + b_in + pos_emb ----------
__global__ __launch_bounds__(128) void embed_kernel(const float* __restrict__ x,
                                                    const float* __restrict__ Win,
                                                    const float* __restrict__ bin,
                                                    float* __restrict__ h) {
  __shared__ float xs[16];
  int m = blockIdx.x, t = threadIdx.x;
  if (t < 16) xs[t] = x[m * 16 + t];
  __syncthreads();
  int l = m & 1023, hi = l >> 5, wi = l & 31;
#pragma unroll
  for (int e0 = 0; e0 < 512; e0 += 128) {
    int e = e0 + t;
    float a = bin[e];
#pragma unroll
    for (int kk = 0; kk < 16; kk++) a += xs[kk] * Win[kk * 512 + e];
    int j = e & 255;
    float p = (e < 256) ? (float)hi : (float)wi;
    float inv = expf((float)j * (-9.210340371976184f / 256.0f));  // 10000^(-j/256)
    a += cosf(p * inv);
    h[(size_t)m * 512 + e] = a;
  }
}

// ---------- layernorm, wave-per-row (no LDS, no barriers): 4 rows/block ----------
__global__ __launch_bounds__(256) void ln_kernel(const float* __restrict__ h,
                                                 const float* __restrict__ gw,
                                                 const float* __restrict__ bw,
                                                 unsigned short* __restrict__ xn) {
  int row = blockIdx.x * 4 + (threadIdx.x >> 6);
  int lane = threadIdx.x & 63;
  const f32x4* hr = (const f32x4*)&h[(size_t)row * 512];
  f32x4 v0 = hr[lane], v1 = hr[lane + 64];
  float s = v0[0]+v0[1]+v0[2]+v0[3] + v1[0]+v1[1]+v1[2]+v1[3];
  float q = v0[0]*v0[0]+v0[1]*v0[1]+v0[2]*v0[2]+v0[3]*v0[3]
          + v1[0]*v1[0]+v1[1]*v1[1]+v1[2]*v1[2]+v1[3]*v1[3];
#pragma unroll
  for (int o = 1; o < 64; o <<= 1) { s += __shfl_xor(s, o); q += __shfl_xor(q, o); }
  float mean = s * (1.0f / 512.0f);
  float var = q * (1.0f / 512.0f) - mean * mean;
  float rstd = rsqrtf(var + 1e-5f);
  f32x4 g0 = ((const f32x4*)gw)[lane], g1 = ((const f32x4*)gw)[lane + 64];
  f32x4 b0 = ((const f32x4*)bw)[lane], b1 = ((const f32x4*)bw)[lane + 64];
  us4 w0, w1;
#pragma unroll
  for (int r = 0; r < 4; r++) {
    w0[r] = f2bf((v0[r] - mean) * rstd * g0[r] + b0[r]);
    w1[r] = f2bf((v1[r] - mean) * rstd * g1[r] + b1[r]);
  }
  *(us4*)&xn[(size_t)row * 512 + lane * 4] = w0;
  *(us4*)&xn[(size_t)row * 512 + 256 + lane * 4] = w1;
}

// ---------- QKV GEMM (reg-staged BK=64, BM=256, 8 waves): V written directly transposed ----------
__global__ __launch_bounds__(512) void qkv_gemm(const unsigned short* __restrict__ xn,
                                                const unsigned short* __restrict__ wtq,
                                                const unsigned short* __restrict__ wtk,
                                                const unsigned short* __restrict__ wtv,
                                                unsigned short* __restrict__ qo,
                                                unsigned short* __restrict__ ko,
                                                unsigned short* __restrict__ vt) {
  __shared__ short8 As[2048];   // 32 subtiles (rg*2+kc), 16x32 fragment-linear
  __shared__ short8 Bs[1024];   // 16 subtiles
  int n0 = blockIdx.x * 128, m0 = blockIdx.y * 256;
  int sel = n0 >> 9;
  const short8* wt = (const short8*)(sel == 0 ? wtq : sel == 1 ? wtk : wtv);
  int nw = n0 & 511;
  const short8* A8 = (const short8*)xn;
  int tid = threadIdx.x, wid = tid >> 6, lane = tid & 63;
  int wr = wid >> 1, wc = wid & 1, c16 = lane & 15, g = lane >> 4;
  const short8* aSrc[4];
  const short8* bSrc[2];
#pragma unroll
  for (int s = 0; s < 4; s++) {
    int sub = wid * 4 + s, rg = sub >> 1, kc = sub & 1;
    aSrc[s] = A8 + (size_t)(m0 + rg * 16 + c16) * 64 + kc * 4 + g;
  }
#pragma unroll
  for (int s = 0; s < 2; s++) {
    int sub = wid * 2 + s, rg = sub >> 1, kc = sub & 1;
    bSrc[s] = wt + (size_t)(nw + rg * 16 + c16) * 64 + kc * 4 + g;
  }
  f32x4 acc[4][4] = {};
  short8 ra[4], rb[2];
#pragma unroll
  for (int s = 0; s < 4; s++) ra[s] = aSrc[s][0];
#pragma unroll
  for (int s = 0; s < 2; s++) rb[s] = bSrc[s][0];
  for (int kt = 0; kt < 8; kt++) {
    __syncthreads();
#pragma unroll
    for (int s = 0; s < 4; s++) As[(wid * 4 + s) * 64 + lane] = ra[s];
#pragma unroll
    for (int s = 0; s < 2; s++) Bs[(wid * 2 + s) * 64 + lane] = rb[s];
    if (kt < 7) {
#pragma unroll
      for (int s = 0; s < 4; s++) ra[s] = aSrc[s][(kt + 1) * 8];
#pragma unroll
      for (int s = 0; s < 2; s++) rb[s] = bSrc[s][(kt + 1) * 8];
    }
    __syncthreads();
#pragma unroll
    for (int kc = 0; kc < 2; kc++) {
      short8 af[4], bf[4];
#pragma unroll
      for (int mf = 0; mf < 4; mf++) af[mf] = As[((wr * 4 + mf) * 2 + kc) * 64 + lane];
#pragma unroll
      for (int nf = 0; nf < 4; nf++) bf[nf] = Bs[((wc * 4 + nf) * 2 + kc) * 64 + lane];
#pragma unroll
      for (int mf = 0; mf < 4; mf++)
#pragma unroll
        for (int nf = 0; nf < 4; nf++)
          acc[mf][nf] = MFMA_BF16(af[mf], bf[nf], acc[mf][nf]);
    }
  }
  if (sel < 2) {
    unsigned short* out = sel == 0 ? qo : ko;
#pragma unroll
    for (int mf = 0; mf < 4; mf++)
#pragma unroll
      for (int nf = 0; nf < 4; nf++) {
        int col = nw + wc * 64 + nf * 16 + c16;
#pragma unroll
        for (int r = 0; r < 4; r++) {
          int row = m0 + wr * 64 + mf * 16 + g * 4 + r;
          out[(size_t)row * 512 + col] = f2bf(acc[mf][nf][r]);
        }
      }
  } else {
    // write V transposed: vt[(b*8+h)*64 + d][l] with l-contiguous 8B stores
    int b8 = (m0 >> 10) * 8;
    int loff = (m0 & 1023) + wr * 64;
#pragma unroll
    for (int mf = 0; mf < 4; mf++)
#pragma unroll
      for (int nf = 0; nf < 4; nf++) {
        int c = nw + wc * 64 + nf * 16 + c16;
        int bh = b8 + (c >> 6), d = c & 63;
        us4 w;
#pragma unroll
        for (int r = 0; r < 4; r++) w[r] = f2bf(acc[mf][nf][r]);
        *(us4*)&vt[(size_t)(bh * 64 + d) * 1024 + loff + mf * 16 + g * 4] = w;
      }
  }
}

// ---------- residual GEMM, K-split: h += A(bf16)[8192,K] @ W, 128x128 per slice, atomicAdd ----------
// blockIdx.z = K-slice; each slice covers nkt64*64 of K.
__global__ __launch_bounds__(256) void gemm_res(const unsigned short* __restrict__ A,
                                                const unsigned short* __restrict__ Wt,
                                                float* __restrict__ h, int Kd8, int nkt64) {
  __shared__ short8 As[1024];
  __shared__ short8 Bs[1024];
  int n0 = blockIdx.x * 128, m0 = blockIdx.y * 128;
  int kofs = blockIdx.z * nkt64 * 8;   // short8 units
  const short8* A8 = (const short8*)A;
  const short8* W8 = (const short8*)Wt;
  int tid = threadIdx.x, wid = tid >> 6, lane = tid & 63;
  int wr = wid >> 1, wc = wid & 1, c16 = lane & 15, g = lane >> 4;
  const short8* aSrc[4];
  const short8* bSrc[4];
#pragma unroll
  for (int s = 0; s < 4; s++) {
    int sub = wid * 4 + s, rg = sub >> 1, kc = sub & 1;
    aSrc[s] = A8 + (size_t)(m0 + rg * 16 + c16) * Kd8 + kofs + kc * 4 + g;
    bSrc[s] = W8 + (size_t)(n0 + rg * 16 + c16) * Kd8 + kofs + kc * 4 + g;
  }
  f32x4 acc[4][4] = {};
  short8 ra[4], rb[4];
#pragma unroll
  for (int s = 0; s < 4; s++) { ra[s] = aSrc[s][0]; rb[s] = bSrc[s][0]; }
  for (int kt = 0; kt < nkt64; kt++) {
    __syncthreads();
#pragma unroll
    for (int s = 0; s < 4; s++) {
      As[(wid * 4 + s) * 64 + lane] = ra[s];
      Bs[(wid * 4 + s) * 64 + lane] = rb[s];
    }
    if (kt + 1 < nkt64) {
#pragma unroll
      for (int s = 0; s < 4; s++) {
        ra[s] = aSrc[s][(kt + 1) * 8];
        rb[s] = bSrc[s][(kt + 1) * 8];
      }
    }
    __syncthreads();
#pragma unroll
    for (int kc = 0; kc < 2; kc++) {
      short8 af[4], bf[4];
#pragma unroll
      for (int mf = 0; mf < 4; mf++) af[mf] = As[((wr * 4 + mf) * 2 + kc) * 64 + lane];
#pragma unroll
      for (int nf = 0; nf < 4; nf++) bf[nf] = Bs[((wc * 4 + nf) * 2 + kc) * 64 + lane];
#pragma unroll
      for (int mf = 0; mf < 4; mf++)
#pragma unroll
        for (int nf = 0; nf < 4; nf++)
          acc[mf][nf] = MFMA_BF16(af[mf], bf[nf], acc[mf][nf]);
    }
  }
#pragma unroll
  for (int mf = 0; mf < 4; mf++)
#pragma unroll
    for (int nf = 0; nf < 4; nf++) {
      int col = n0 + wc * 64 + nf * 16 + c16;
#pragma unroll
      for (int r = 0; r < 4; r++) {
        int row = m0 + wr * 64 + mf * 16 + g * 4 + r;
        atomicAdd(&h[(size_t)row * 512 + col], acc[mf][nf][r]);
      }
    }
}

// ---------- FFN fused dual GEMM, reg-staged BK=64, BM=256, 8 waves ----------
__global__ __launch_bounds__(512) void ffn_gemm(const unsigned short* __restrict__ xn,
                                                const unsigned short* __restrict__ w1t,
                                                const unsigned short* __restrict__ w2t,
                                                unsigned short* __restrict__ gout) {
  __shared__ short8 As[2048];    // 32 subtiles
  __shared__ short8 B1s[1024];   // 16 subtiles
  __shared__ short8 B2s[1024];
  int n0 = blockIdx.x * 128, m0 = blockIdx.y * 256;
  const short8* A8 = (const short8*)xn;
  const short8* W18 = (const short8*)w1t;
  const short8* W28 = (const short8*)w2t;
  int tid = threadIdx.x, wid = tid >> 6, lane = tid & 63;
  int wr = wid >> 1, wc = wid & 1, c16 = lane & 15, g = lane >> 4;
  const short8* aSrc[4];
  const short8* b1Src[2];
  const short8* b2Src[2];
#pragma unroll
  for (int s = 0; s < 4; s++) {
    int sub = wid * 4 + s, rg = sub >> 1, kc = sub & 1;
    aSrc[s] = A8 + (size_t)(m0 + rg * 16 + c16) * 64 + kc * 4 + g;
  }
#pragma unroll
  for (int s = 0; s < 2; s++) {
    int sub = wid * 2 + s, rg = sub >> 1, kc = sub & 1;
    b1Src[s] = W18 + (size_t)(n0 + rg * 16 + c16) * 64 + kc * 4 + g;
    b2Src[s] = W28 + (size_t)(n0 + rg * 16 + c16) * 64 + kc * 4 + g;
  }
  f32x4 acc1[4][4] = {};
  f32x4 acc2[4][4] = {};
  short8 ra[4], rb1[2], rb2[2];
#pragma unroll
  for (int s = 0; s < 4; s++) ra[s] = aSrc[s][0];
#pragma unroll
  for (int s = 0; s < 2; s++) { rb1[s] = b1Src[s][0]; rb2[s] = b2Src[s][0]; }
  for (int kt = 0; kt < 8; kt++) {
    __syncthreads();
#pragma unroll
    for (int s = 0; s < 4; s++) As[(wid * 4 + s) * 64 + lane] = ra[s];
#pragma unroll
    for (int s = 0; s < 2; s++) {
      B1s[(wid * 2 + s) * 64 + lane] = rb1[s];
      B2s[(wid * 2 + s) * 64 + lane] = rb2[s];
    }
    if (kt < 7) {
#pragma unroll
      for (int s = 0; s < 4; s++) ra[s] = aSrc[s][(kt + 1) * 8];
#pragma unroll
      for (int s = 0; s < 2; s++) {
        rb1[s] = b1Src[s][(kt + 1) * 8];
        rb2[s] = b2Src[s][(kt + 1) * 8];
      }
    }
    __syncthreads();
#pragma unroll
    for (int kc = 0; kc < 2; kc++) {
      short8 af[4], b1f[4], b2f[4];
#pragma unroll
      for (int mf = 0; mf < 4; mf++) af[mf] = As[((wr * 4 + mf) * 2 + kc) * 64 + lane];
#pragma unroll
      for (int nf = 0; nf < 4; nf++) {
        b1f[nf] = B1s[((wc * 4 + nf) * 2 + kc) * 64 + lane];
        b2f[nf] = B2s[((wc * 4 + nf) * 2 + kc) * 64 + lane];
      }
#pragma unroll
      for (int mf = 0; mf < 4; mf++)
#pragma unroll
        for (int nf = 0; nf < 4; nf++) {
          acc1[mf][nf] = MFMA_BF16(af[mf], b1f[nf], acc1[mf][nf]);
          acc2[mf][nf] = MFMA_BF16(af[mf], b2f[nf], acc2[mf][nf]);
        }
    }
  }
#pragma unroll
  for (int mf = 0; mf < 4; mf++)
#pragma unroll
    for (int nf = 0; nf < 4; nf++) {
      int col = n0 + wc * 64 + nf * 16 + c16;
#pragma unroll
      for (int r = 0; r < 4; r++) {
        int row = m0 + wr * 64 + mf * 16 + g * 4 + r;
        float xx = acc1[mf][nf][r];
        float yy = acc2[mf][nf][r];
        float sg = xx / (1.0f + __expf(-xx));
        gout[(size_t)row * 2048 + col] = f2bf(sg * yy);
      }
    }
}

// ---------- flash attention: log2-domain softmax + defer-rescale + cvt_pk P-pack ----------
__global__ __launch_bounds__(256) void attn_kernel(const unsigned short* __restrict__ q,
                                                   const unsigned short* __restrict__ k,
                                                   const unsigned short* __restrict__ vt,
                                                   const int* __restrict__ tmsk,
                                                   unsigned short* __restrict__ o) {
  __shared__ short8 Ks[512];
  __shared__ short8 Vs[512];
  __shared__ uint2  Pb[2048];
  __shared__ f32x4  maskv[256];

  int s = xcd_swz((int)blockIdx.x, 512);
  int qb = s & 7;
  int bh = s >> 3;
  int b = bh >> 3, hh = bh & 7;
  int tid = threadIdx.x, wid = tid >> 6, lane = tid & 63;
  int c16 = lane & 15, gq = lane >> 4;
  int qrow0 = qb * 128 + wid * 32;

  const short8* q8 = (const short8*)q;
  const short8* k8 = (const short8*)k;
  const short8* v8 = (const short8*)vt;

  short8 qf[2][2];
#pragma unroll
  for (int nf = 0; nf < 2; nf++)
#pragma unroll
    for (int dc = 0; dc < 2; dc++)
      qf[nf][dc] = q8[(size_t)(b * 1024 + qrow0 + nf * 16 + c16) * 64 + hh * 8 + dc * 4 + gq];

  {
    int4 mm = ((const int4*)(tmsk + b * 1024))[tid];
    f32x4 ma;
    // mask pre-multiplied by log2(e) (log2-domain softmax)
    ma[0] = (mm.x == 0) ? -1.442695e9f : 0.0f;
    ma[1] = (mm.y == 0) ? -1.442695e9f : 0.0f;
    ma[2] = (mm.z == 0) ? -1.442695e9f : 0.0f;
    ma[3] = (mm.w == 0) ? -1.442695e9f : 0.0f;
    maskv[tid] = ma;
  }

  short8 rk[2], rv[2];
#pragma unroll
  for (int ss = 0; ss < 2; ss++) {
    int sub = wid * 2 + ss;
    rk[ss] = k8[(size_t)(b * 1024 + (sub >> 1) * 16 + c16) * 64 + hh * 8 + (sub & 1) * 4 + gq];
    rv[ss] = v8[(size_t)(bh * 64 + (sub >> 1) * 16 + c16) * 128 + (sub & 1) * 4 + gq];
  }

  float mrun[2] = {-1e30f, -1e30f};
  float lrun[2] = {0.0f, 0.0f};
  f32x4 accO[4][2] = {};
  const float SCL = 0.125f * 1.4426950408889634f;  // scale * log2(e)

  for (int kt = 0; kt < 16; kt++) {
    __syncthreads();
#pragma unroll
    for (int ss = 0; ss < 2; ss++) {
      int sub = wid * 2 + ss;
      Ks[sub * 64 + lane] = rk[ss];
      Vs[sub * 64 + lane] = rv[ss];
    }
    if (kt < 15) {
      int kt2 = kt + 1;
#pragma unroll
      for (int ss = 0; ss < 2; ss++) {
        int sub = wid * 2 + ss;
        rk[ss] = k8[(size_t)(b * 1024 + kt2 * 64 + (sub >> 1) * 16 + c16) * 64 + hh * 8 + (sub & 1) * 4 + gq];
        rv[ss] = v8[(size_t)(bh * 64 + (sub >> 1) * 16 + c16) * 128 + kt2 * 8 + (sub & 1) * 4 + gq];
      }
    }
    __syncthreads();

    f32x4 sT[4][2] = {};
#pragma unroll
    for (int mf = 0; mf < 4; mf++) {
      short8 ka0 = Ks[(mf * 2 + 0) * 64 + lane];
      short8 ka1 = Ks[(mf * 2 + 1) * 64 + lane];
#pragma unroll
      for (int nf = 0; nf < 2; nf++) {
        sT[mf][nf] = MFMA_BF16(ka0, qf[nf][0], sT[mf][nf]);
        sT[mf][nf] = MFMA_BF16(ka1, qf[nf][1], sT[mf][nf]);
      }
    }

#pragma unroll
    for (int nf = 0; nf < 2; nf++) {
      float pv[4][4];
      float tm = -1e30f;
#pragma unroll
      for (int mf = 0; mf < 4; mf++) {
        f32x4 mk = maskv[kt * 16 + mf * 4 + gq];
#pragma unroll
        for (int r = 0; r < 4; r++) {
          float sv = sT[mf][nf][r] * SCL + mk[r];
          pv[mf][r] = sv;
          tm = fmaxf(tm, sv);
        }
      }
      tm = fmaxf(tm, __shfl_xor(tm, 16));
      tm = fmaxf(tm, __shfl_xor(tm, 32));
      // defer-rescale (T13): skip when tile max within 8 of running max
      if (!__all(tm - mrun[nf] <= 8.0f)) {
        float mn = fmaxf(mrun[nf], tm);
        float fac = exp2f(mrun[nf] - mn);
        mrun[nf] = mn;
        lrun[nf] *= fac;
#pragma unroll
        for (int dmf = 0; dmf < 4; dmf++) accO[dmf][nf] *= fac;
      }
      float ts = 0.0f;
#pragma unroll
      for (int mf = 0; mf < 4; mf++)
#pragma unroll
        for (int r = 0; r < 4; r++) {
          float p = exp2f(pv[mf][r] - mrun[nf]);
          pv[mf][r] = p;
          ts += p;
        }
      ts += __shfl_xor(ts, 16);
      ts += __shfl_xor(ts, 32);
      lrun[nf] += ts;
#pragma unroll
      for (int mf = 0; mf < 4; mf++) {
        unsigned lo = cvt_pk_bf16(pv[mf][0], pv[mf][1]);
        unsigned hi = cvt_pk_bf16(pv[mf][2], pv[mf][3]);
        int kk = mf >> 1;
        int gr = (mf & 1) * 2 + (gq >> 1);
        uint2 t2; t2.x = lo; t2.y = hi;
        Pb[wid * 512 + ((nf * 2 + kk) * 64 + gr * 16 + c16) * 2 + (gq & 1)] = t2;
      }
    }
    __syncthreads();

    const short8* Pb8 = (const short8*)Pb;
#pragma unroll
    for (int nf = 0; nf < 2; nf++) {
      short8 pb0 = Pb8[wid * 256 + (nf * 2 + 0) * 64 + lane];
      short8 pb1 = Pb8[wid * 256 + (nf * 2 + 1) * 64 + lane];
#pragma unroll
      for (int dmf = 0; dmf < 4; dmf++) {
        short8 va0 = Vs[(dmf * 2 + 0) * 64 + lane];
        short8 va1 = Vs[(dmf * 2 + 1) * 64 + lane];
        accO[dmf][nf] = MFMA_BF16(va0, pb0, accO[dmf][nf]);
        accO[dmf][nf] = MFMA_BF16(va1, pb1, accO[dmf][nf]);
      }
    }
  }

#pragma unroll
  for (int nf = 0; nf < 2; nf++) {
    float inv = 1.0f / lrun[nf];
    int row = b * 1024 + qrow0 + nf * 16 + c16;
#pragma unroll
    for (int dmf = 0; dmf < 4; dmf++) {
      us4 w;
#pragma unroll
      for (int r = 0; r < 4; r++) w[r] = f2bf(accO[dmf][nf][r] * inv);
      *(us4*)&o[(size_t)row * 512 + hh * 64 + dmf * 16 + gq * 4] = w;
    }
  }
}

// ---------- final: out[8192,16] = h @ W_out + b_out ----------
__global__ __launch_bounds__(128) void out_kernel(const float* __restrict__ h,
                                                  const float* __restrict__ Wout,
                                                  const float* __restrict__ bout,
                                                  float* __restrict__ out) {
  __shared__ f32x4 hs4[8][128];
  __shared__ f32x4 Ws4[16][129];
  int t = threadIdx.x;
  int rb = blockIdx.x * 8;
  float* hsf = (float*)hs4;
  float* wsf = (float*)Ws4;
  for (int i = t; i < 4096; i += 128) hsf[i] = h[(size_t)rb * 512 + i];
  for (int i = t; i < 8192; i += 128) wsf[(i & 15) * 516 + (i >> 4)] = Wout[i];
  __syncthreads();
  int r = t >> 4, c = t & 15;
  float acc = bout[c];
  for (int k4 = 0; k4 < 128; k4++) {
    f32x4 a = hs4[r][k4];
    f32x4 w = Ws4[c][k4];
    acc += a[0]*w[0] + a[1]*w[1] + a[2]*w[2] + a[3]*w[3];
  }
  out[(rb + r) * 16 + c] = acc;
}

extern "C" void kernel_launch(void* const* d_in, const int* in_sizes, int n_in,
                              void* d_out, int out_size, void* d_ws, size_t ws_size,
                              hipStream_t stream) {
  const float* x    = (const float*)d_in[0];
  const int*   tmsk = (const int*)d_in[1];
  const float* Win  = (const float*)d_in[2];
  const float* bin  = (const float*)d_in[3];
  const float* ln1g = (const float*)d_in[4];
  const float* ln1b = (const float*)d_in[5];
  const float* Wq   = (const float*)d_in[6];
  const float* Wk   = (const float*)d_in[7];
  const float* Wv   = (const float*)d_in[8];
  const float* Wo   = (const float*)d_in[9];
  const float* ln2g = (const float*)d_in[10];
  const float* ln2b = (const float*)d_in[11];
  const float* W1   = (const float*)d_in[12];
  const float* W2   = (const float*)d_in[13];
  const float* W3   = (const float*)d_in[14];
  const float* Wout = (const float*)d_in[15];
  const float* bout = (const float*)d_in[16];
  float* outp = (float*)d_out;

  char* ws = (char*)d_ws;
  unsigned short* wtq = (unsigned short*)(ws + 0);
  unsigned short* wtk = (unsigned short*)(ws + 6291456);
  unsigned short* wtv = (unsigned short*)(ws + 12582912);
  unsigned short* wto = (unsigned short*)(ws + 18874368);
  unsigned short* wt1 = (unsigned short*)(ws + 25165824);
  unsigned short* wt2 = (unsigned short*)(ws + 50331648);
  unsigned short* wt3 = (unsigned short*)(ws + 75497472);
  float*          h   = (float*)(ws + 100663296);
  unsigned short* xn  = (unsigned short*)(ws + 117440512);
  unsigned short* qb  = (unsigned short*)(ws + 125829120);
  unsigned short* kb  = (unsigned short*)(ws + 134217728);
  unsigned short* vtb = (unsigned short*)(ws + 150994944);
  unsigned short* ob  = (unsigned short*)(ws + 159383552);
  unsigned short* gb  = (unsigned short*)(ws + 167772160);

  dim3 tb(32, 8);
  wtrans_kernel<<<dim3(16, 16, 12), tb, 0, stream>>>(Wq, wtq, 512, 512);
  wtrans_kernel<<<dim3(16, 16, 12), tb, 0, stream>>>(Wk, wtk, 512, 512);
  wtrans_kernel<<<dim3(16, 16, 12), tb, 0, stream>>>(Wv, wtv, 512, 512);
  wtrans_kernel<<<dim3(16, 16, 12), tb, 0, stream>>>(Wo, wto, 512, 512);
  wtrans_kernel<<<dim3(64, 16, 12), tb, 0, stream>>>(W1, wt1, 512, 2048);
  wtrans_kernel<<<dim3(64, 16, 12), tb, 0, stream>>>(W2, wt2, 512, 2048);
  wtrans_kernel<<<dim3(16, 64, 12), tb, 0, stream>>>(W3, wt3, 2048, 512);

  embed_kernel<<<8192, 128, 0, stream>>>(x, Win, bin, h);

  for (int l = 0; l < 12; l++) {
    ln_kernel<<<2048, 256, 0, stream>>>(h, ln1g + l * 512, ln1b + l * 512, xn);
    qkv_gemm<<<dim3(12, 32), 512, 0, stream>>>(xn,
        wtq + (size_t)l * 262144, wtk + (size_t)l * 262144, wtv + (size_t)l * 262144,
        qb, kb, vtb);
    attn_kernel<<<512, 256, 0, stream>>>(qb, kb, vtb, tmsk, ob);
    gemm_res<<<dim3(4, 64, 2), 256, 0, stream>>>(ob, wto + (size_t)l * 262144, h, 64, 4);
    ln_kernel<<<2048, 256, 0, stream>>>(h, ln2g + l * 512, ln2b + l * 512, xn);
    ffn_gemm<<<dim3(16, 32), 512, 0, stream>>>(xn,
        wt1 + (size_t)l * 1048576, wt2 + (size_t)l * 1048576, gb);
    gemm_res<<<dim3(4, 64, 4), 256, 0, stream>>>(gb, wt3 + (size_t)l * 1048576, h, 256, 8);
  }
  out_kernel<<<1024, 128, 0, stream>>>(h, Wout, bout, outp);

  (void)in_sizes; (void)n_in; (void)out_size; (void)ws_size;
}

// Round 13
// 2440.104 us; speedup vs baseline: 1.2047x; 1.2047x over previous
//
#include <hip/hip_runtime.h>

typedef __attribute__((ext_vector_type(8))) short short8;
typedef __attribute__((ext_vector_type(4))) float f32x4;
typedef __attribute__((ext_vector_type(4))) unsigned short us4;

#define MFMA_BF16(a,b,c) __builtin_amdgcn_mfma_f32_16x16x32_bf16((a),(b),(c),0,0,0)

__device__ __forceinline__ unsigned short f2bf(float f) {
  unsigned int u = __float_as_uint(f);
  u += 0x7fffu + ((u >> 16) & 1u);   // round-to-nearest-even
  return (unsigned short)(u >> 16);
}

// pack two f32 -> two bf16 in one instruction
__device__ __forceinline__ unsigned cvt_pk_bf16(float lo, float hi) {
  unsigned r;
  asm("v_cvt_pk_bf16_f32 %0, %1, %2" : "=v"(r) : "v"(lo), "v"(hi));
  return r;
}

// bijective XCD-chunk swizzle (attention only)
__device__ __forceinline__ int xcd_swz(int lid, int nwg) {
  return (lid & 7) * (nwg >> 3) + (lid >> 3);
}

// ---------- weight transpose + f32->bf16: src f32 [R][C] -> dst bf16 [C][R], batched over z ----------
__global__ __launch_bounds__(256) void wtrans_kernel(const float* __restrict__ src,
                                                     unsigned short* __restrict__ dst,
                                                     int R, int C) {
  __shared__ float tile[32][33];
  int c0 = blockIdx.x * 32, r0 = blockIdx.y * 32;
  const float* s = src + (size_t)blockIdx.z * R * C;
  unsigned short* d = dst + (size_t)blockIdx.z * R * C;
  int tx = threadIdx.x, ty = threadIdx.y;
#pragma unroll
  for (int i = 0; i < 32; i += 8)
    tile[ty + i][tx] = s[(size_t)(r0 + ty + i) * C + c0 + tx];
  __syncthreads();
#pragma unroll
  for (int i = 0; i < 32; i += 8)
    d[(size_t)(c0 + ty + i) * R + r0 + tx] = f2bf(tile[tx][ty + i]);
}

// ---------- embed: h = x @ W_in + b_in + pos_emb ----------
__global__ __launch_bounds__(128) void embed_kernel(const float* __restrict__ x,
                                                    const float* __restrict__ Win,
                                                    const float* __restrict__ bin,
                                                    float* __restrict__ h) {
  __shared__ float xs[16];
  int m = blockIdx.x, t = threadIdx.x;
  if (t < 16) xs[t] = x[m * 16 + t];
  __syncthreads();
  int l = m & 1023, hi = l >> 5, wi = l & 31;
#pragma unroll
  for (int e0 = 0; e0 < 512; e0 += 128) {
    int e = e0 + t;
    float a = bin[e];
#pragma unroll
    for (int kk = 0; kk < 16; kk++) a += xs[kk] * Win[kk * 512 + e];
    int j = e & 255;
    float p = (e < 256) ? (float)hi : (float)wi;
    float inv = expf((float)j * (-9.210340371976184f / 256.0f));  // 10000^(-j/256)
    a += cosf(p * inv);
    h[(size_t)m * 512 + e] = a;
  }
}

// ---------- layernorm, wave-per-row (no LDS, no barriers): 4 rows/block ----------
__global__ __launch_bounds__(256) void ln_kernel(const float* __restrict__ h,
                                                 const float* __restrict__ gw,
                                                 const float* __restrict__ bw,
                                                 unsigned short* __restrict__ xn) {
  int row = blockIdx.x * 4 + (threadIdx.x >> 6);
  int lane = threadIdx.x & 63;
  const f32x4* hr = (const f32x4*)&h[(size_t)row * 512];
  f32x4 v0 = hr[lane], v1 = hr[lane + 64];
  float s = v0[0]+v0[1]+v0[2]+v0[3] + v1[0]+v1[1]+v1[2]+v1[3];
  float q = v0[0]*v0[0]+v0[1]*v0[1]+v0[2]*v0[2]+v0[3]*v0[3]
          + v1[0]*v1[0]+v1[1]*v1[1]+v1[2]*v1[2]+v1[3]*v1[3];
#pragma unroll
  for (int o = 1; o < 64; o <<= 1) { s += __shfl_xor(s, o); q += __shfl_xor(q, o); }
  float mean = s * (1.0f / 512.0f);
  float var = q * (1.0f / 512.0f) - mean * mean;
  float rstd = rsqrtf(var + 1e-5f);
  f32x4 g0 = ((const f32x4*)gw)[lane], g1 = ((const f32x4*)gw)[lane + 64];
  f32x4 b0 = ((const f32x4*)bw)[lane], b1 = ((const f32x4*)bw)[lane + 64];
  us4 w0, w1;
#pragma unroll
  for (int r = 0; r < 4; r++) {
    w0[r] = f2bf((v0[r] - mean) * rstd * g0[r] + b0[r]);
    w1[r] = f2bf((v1[r] - mean) * rstd * g1[r] + b1[r]);
  }
  *(us4*)&xn[(size_t)row * 512 + lane * 4] = w0;
  *(us4*)&xn[(size_t)row * 512 + 256 + lane * 4] = w1;
}

// ---------- QKV GEMM (reg-staged BK=64, BM=256, 8 waves): V written directly transposed ----------
__global__ __launch_bounds__(512) void qkv_gemm(const unsigned short* __restrict__ xn,
                                                const unsigned short* __restrict__ wtq,
                                                const unsigned short* __restrict__ wtk,
                                                const unsigned short* __restrict__ wtv,
                                                unsigned short* __restrict__ qo,
                                                unsigned short* __restrict__ ko,
                                                unsigned short* __restrict__ vt) {
  __shared__ short8 As[2048];   // 32 subtiles (rg*2+kc), 16x32 fragment-linear
  __shared__ short8 Bs[1024];   // 16 subtiles
  int n0 = blockIdx.x * 128, m0 = blockIdx.y * 256;
  int sel = n0 >> 9;
  const short8* wt = (const short8*)(sel == 0 ? wtq : sel == 1 ? wtk : wtv);
  int nw = n0 & 511;
  const short8* A8 = (const short8*)xn;
  int tid = threadIdx.x, wid = tid >> 6, lane = tid & 63;
  int wr = wid >> 1, wc = wid & 1, c16 = lane & 15, g = lane >> 4;
  const short8* aSrc[4];
  const short8* bSrc[2];
#pragma unroll
  for (int s = 0; s < 4; s++) {
    int sub = wid * 4 + s, rg = sub >> 1, kc = sub & 1;
    aSrc[s] = A8 + (size_t)(m0 + rg * 16 + c16) * 64 + kc * 4 + g;
  }
#pragma unroll
  for (int s = 0; s < 2; s++) {
    int sub = wid * 2 + s, rg = sub >> 1, kc = sub & 1;
    bSrc[s] = wt + (size_t)(nw + rg * 16 + c16) * 64 + kc * 4 + g;
  }
  f32x4 acc[4][4] = {};
  short8 ra[4], rb[2];
#pragma unroll
  for (int s = 0; s < 4; s++) ra[s] = aSrc[s][0];
#pragma unroll
  for (int s = 0; s < 2; s++) rb[s] = bSrc[s][0];
  for (int kt = 0; kt < 8; kt++) {
    __syncthreads();
#pragma unroll
    for (int s = 0; s < 4; s++) As[(wid * 4 + s) * 64 + lane] = ra[s];
#pragma unroll
    for (int s = 0; s < 2; s++) Bs[(wid * 2 + s) * 64 + lane] = rb[s];
    if (kt < 7) {
#pragma unroll
      for (int s = 0; s < 4; s++) ra[s] = aSrc[s][(kt + 1) * 8];
#pragma unroll
      for (int s = 0; s < 2; s++) rb[s] = bSrc[s][(kt + 1) * 8];
    }
    __syncthreads();
#pragma unroll
    for (int kc = 0; kc < 2; kc++) {
      short8 af[4], bf[4];
#pragma unroll
      for (int mf = 0; mf < 4; mf++) af[mf] = As[((wr * 4 + mf) * 2 + kc) * 64 + lane];
#pragma unroll
      for (int nf = 0; nf < 4; nf++) bf[nf] = Bs[((wc * 4 + nf) * 2 + kc) * 64 + lane];
#pragma unroll
      for (int mf = 0; mf < 4; mf++)
#pragma unroll
        for (int nf = 0; nf < 4; nf++)
          acc[mf][nf] = MFMA_BF16(af[mf], bf[nf], acc[mf][nf]);
    }
  }
  if (sel < 2) {
    unsigned short* out = sel == 0 ? qo : ko;
#pragma unroll
    for (int mf = 0; mf < 4; mf++)
#pragma unroll
      for (int nf = 0; nf < 4; nf++) {
        int col = nw + wc * 64 + nf * 16 + c16;
#pragma unroll
        for (int r = 0; r < 4; r++) {
          int row = m0 + wr * 64 + mf * 16 + g * 4 + r;
          out[(size_t)row * 512 + col] = f2bf(acc[mf][nf][r]);
        }
      }
  } else {
    // write V transposed: vt[(b*8+h)*64 + d][l] with l-contiguous 8B stores
    int b8 = (m0 >> 10) * 8;
    int loff = (m0 & 1023) + wr * 64;
#pragma unroll
    for (int mf = 0; mf < 4; mf++)
#pragma unroll
      for (int nf = 0; nf < 4; nf++) {
        int c = nw + wc * 64 + nf * 16 + c16;
        int bh = b8 + (c >> 6), d = c & 63;
        us4 w;
#pragma unroll
        for (int r = 0; r < 4; r++) w[r] = f2bf(acc[mf][nf][r]);
        *(us4*)&vt[(size_t)(bh * 64 + d) * 1024 + loff + mf * 16 + g * 4] = w;
      }
  }
}

// ---------- residual GEMM: h += A(bf16)[8192,K] @ W, BM=128 BN=64, reg-staged BK=64 ----------
// grid (8, 64) = 512 blocks (2 blocks/CU). Exclusive output tiles, plain += epilogue.
__global__ __launch_bounds__(256) void gemm_res(const unsigned short* __restrict__ A,
                                                const unsigned short* __restrict__ Wt,
                                                float* __restrict__ h, int Kd8, int nkt64) {
  __shared__ short8 As[1024];   // 16 subtiles
  __shared__ short8 Bs[512];    // 8 subtiles
  int n0 = blockIdx.x * 64, m0 = blockIdx.y * 128;
  const short8* A8 = (const short8*)A;
  const short8* W8 = (const short8*)Wt;
  int tid = threadIdx.x, wid = tid >> 6, lane = tid & 63;
  int wr = wid >> 1, wc = wid & 1, c16 = lane & 15, g = lane >> 4;
  const short8* aSrc[4];
  const short8* bSrc[2];
#pragma unroll
  for (int s = 0; s < 4; s++) {
    int sub = wid * 4 + s, rg = sub >> 1, kc = sub & 1;
    aSrc[s] = A8 + (size_t)(m0 + rg * 16 + c16) * Kd8 + kc * 4 + g;
  }
#pragma unroll
  for (int s = 0; s < 2; s++) {
    int sub = wid * 2 + s, rg = sub >> 1, kc = sub & 1;
    bSrc[s] = W8 + (size_t)(n0 + rg * 16 + c16) * Kd8 + kc * 4 + g;
  }
  f32x4 acc[4][2] = {};
  short8 ra[4], rb[2];
#pragma unroll
  for (int s = 0; s < 4; s++) ra[s] = aSrc[s][0];
#pragma unroll
  for (int s = 0; s < 2; s++) rb[s] = bSrc[s][0];
  for (int kt = 0; kt < nkt64; kt++) {
    __syncthreads();
#pragma unroll
    for (int s = 0; s < 4; s++) As[(wid * 4 + s) * 64 + lane] = ra[s];
#pragma unroll
    for (int s = 0; s < 2; s++) Bs[(wid * 2 + s) * 64 + lane] = rb[s];
    if (kt + 1 < nkt64) {
#pragma unroll
      for (int s = 0; s < 4; s++) ra[s] = aSrc[s][(kt + 1) * 8];
#pragma unroll
      for (int s = 0; s < 2; s++) rb[s] = bSrc[s][(kt + 1) * 8];
    }
    __syncthreads();
#pragma unroll
    for (int kc = 0; kc < 2; kc++) {
      short8 af[4], bf[2];
#pragma unroll
      for (int mf = 0; mf < 4; mf++) af[mf] = As[((wr * 4 + mf) * 2 + kc) * 64 + lane];
#pragma unroll
      for (int nf = 0; nf < 2; nf++) bf[nf] = Bs[((wc * 2 + nf) * 2 + kc) * 64 + lane];
#pragma unroll
      for (int mf = 0; mf < 4; mf++)
#pragma unroll
        for (int nf = 0; nf < 2; nf++)
          acc[mf][nf] = MFMA_BF16(af[mf], bf[nf], acc[mf][nf]);
    }
  }
#pragma unroll
  for (int mf = 0; mf < 4; mf++)
#pragma unroll
    for (int nf = 0; nf < 2; nf++) {
      int col = n0 + wc * 32 + nf * 16 + c16;
#pragma unroll
      for (int r = 0; r < 4; r++) {
        int row = m0 + wr * 64 + mf * 16 + g * 4 + r;
        h[(size_t)row * 512 + col] += acc[mf][nf][r];
      }
    }
}

// ---------- FFN fused dual GEMM, reg-staged BK=64, BM=256, 8 waves ----------
__global__ __launch_bounds__(512) void ffn_gemm(const unsigned short* __restrict__ xn,
                                                const unsigned short* __restrict__ w1t,
                                                const unsigned short* __restrict__ w2t,
                                                unsigned short* __restrict__ gout) {
  __shared__ short8 As[2048];    // 32 subtiles
  __shared__ short8 B1s[1024];   // 16 subtiles
  __shared__ short8 B2s[1024];
  int n0 = blockIdx.x * 128, m0 = blockIdx.y * 256;
  const short8* A8 = (const short8*)xn;
  const short8* W18 = (const short8*)w1t;
  const short8* W28 = (const short8*)w2t;
  int tid = threadIdx.x, wid = tid >> 6, lane = tid & 63;
  int wr = wid >> 1, wc = wid & 1, c16 = lane & 15, g = lane >> 4;
  const short8* aSrc[4];
  const short8* b1Src[2];
  const short8* b2Src[2];
#pragma unroll
  for (int s = 0; s < 4; s++) {
    int sub = wid * 4 + s, rg = sub >> 1, kc = sub & 1;
    aSrc[s] = A8 + (size_t)(m0 + rg * 16 + c16) * 64 + kc * 4 + g;
  }
#pragma unroll
  for (int s = 0; s < 2; s++) {
    int sub = wid * 2 + s, rg = sub >> 1, kc = sub & 1;
    b1Src[s] = W18 + (size_t)(n0 + rg * 16 + c16) * 64 + kc * 4 + g;
    b2Src[s] = W28 + (size_t)(n0 + rg * 16 + c16) * 64 + kc * 4 + g;
  }
  f32x4 acc1[4][4] = {};
  f32x4 acc2[4][4] = {};
  short8 ra[4], rb1[2], rb2[2];
#pragma unroll
  for (int s = 0; s < 4; s++) ra[s] = aSrc[s][0];
#pragma unroll
  for (int s = 0; s < 2; s++) { rb1[s] = b1Src[s][0]; rb2[s] = b2Src[s][0]; }
  for (int kt = 0; kt < 8; kt++) {
    __syncthreads();
#pragma unroll
    for (int s = 0; s < 4; s++) As[(wid * 4 + s) * 64 + lane] = ra[s];
#pragma unroll
    for (int s = 0; s < 2; s++) {
      B1s[(wid * 2 + s) * 64 + lane] = rb1[s];
      B2s[(wid * 2 + s) * 64 + lane] = rb2[s];
    }
    if (kt < 7) {
#pragma unroll
      for (int s = 0; s < 4; s++) ra[s] = aSrc[s][(kt + 1) * 8];
#pragma unroll
      for (int s = 0; s < 2; s++) {
        rb1[s] = b1Src[s][(kt + 1) * 8];
        rb2[s] = b2Src[s][(kt + 1) * 8];
      }
    }
    __syncthreads();
#pragma unroll
    for (int kc = 0; kc < 2; kc++) {
      short8 af[4], b1f[4], b2f[4];
#pragma unroll
      for (int mf = 0; mf < 4; mf++) af[mf] = As[((wr * 4 + mf) * 2 + kc) * 64 + lane];
#pragma unroll
      for (int nf = 0; nf < 4; nf++) {
        b1f[nf] = B1s[((wc * 4 + nf) * 2 + kc) * 64 + lane];
        b2f[nf] = B2s[((wc * 4 + nf) * 2 + kc) * 64 + lane];
      }
#pragma unroll
      for (int mf = 0; mf < 4; mf++)
#pragma unroll
        for (int nf = 0; nf < 4; nf++) {
          acc1[mf][nf] = MFMA_BF16(af[mf], b1f[nf], acc1[mf][nf]);
          acc2[mf][nf] = MFMA_BF16(af[mf], b2f[nf], acc2[mf][nf]);
        }
    }
  }
#pragma unroll
  for (int mf = 0; mf < 4; mf++)
#pragma unroll
    for (int nf = 0; nf < 4; nf++) {
      int col = n0 + wc * 64 + nf * 16 + c16;
#pragma unroll
      for (int r = 0; r < 4; r++) {
        int row = m0 + wr * 64 + mf * 16 + g * 4 + r;
        float xx = acc1[mf][nf][r];
        float yy = acc2[mf][nf][r];
        float sg = xx / (1.0f + __expf(-xx));
        gout[(size_t)row * 2048 + col] = f2bf(sg * yy);
      }
    }
}

// ---------- flash attention: log2-domain softmax + defer-rescale + cvt_pk P-pack ----------
__global__ __launch_bounds__(256) void attn_kernel(const unsigned short* __restrict__ q,
                                                   const unsigned short* __restrict__ k,
                                                   const unsigned short* __restrict__ vt,
                                                   const int* __restrict__ tmsk,
                                                   unsigned short* __restrict__ o) {
  __shared__ short8 Ks[512];
  __shared__ short8 Vs[512];
  __shared__ uint2  Pb[2048];
  __shared__ f32x4  maskv[256];

  int s = xcd_swz((int)blockIdx.x, 512);
  int qb = s & 7;
  int bh = s >> 3;
  int b = bh >> 3, hh = bh & 7;
  int tid = threadIdx.x, wid = tid >> 6, lane = tid & 63;
  int c16 = lane & 15, gq = lane >> 4;
  int qrow0 = qb * 128 + wid * 32;

  const short8* q8 = (const short8*)q;
  const short8* k8 = (const short8*)k;
  const short8* v8 = (const short8*)vt;

  short8 qf[2][2];
#pragma unroll
  for (int nf = 0; nf < 2; nf++)
#pragma unroll
    for (int dc = 0; dc < 2; dc++)
      qf[nf][dc] = q8[(size_t)(b * 1024 + qrow0 + nf * 16 + c16) * 64 + hh * 8 + dc * 4 + gq];

  {
    int4 mm = ((const int4*)(tmsk + b * 1024))[tid];
    f32x4 ma;
    ma[0] = (mm.x == 0) ? -1.442695e9f : 0.0f;
    ma[1] = (mm.y == 0) ? -1.442695e9f : 0.0f;
    ma[2] = (mm.z == 0) ? -1.442695e9f : 0.0f;
    ma[3] = (mm.w == 0) ? -1.442695e9f : 0.0f;
    maskv[tid] = ma;
  }

  short8 rk[2], rv[2];
#pragma unroll
  for (int ss = 0; ss < 2; ss++) {
    int sub = wid * 2 + ss;
    rk[ss] = k8[(size_t)(b * 1024 + (sub >> 1) * 16 + c16) * 64 + hh * 8 + (sub & 1) * 4 + gq];
    rv[ss] = v8[(size_t)(bh * 64 + (sub >> 1) * 16 + c16) * 128 + (sub & 1) * 4 + gq];
  }

  float mrun[2] = {-1e30f, -1e30f};
  float lrun[2] = {0.0f, 0.0f};
  f32x4 accO[4][2] = {};
  const float SCL = 0.125f * 1.4426950408889634f;  // scale * log2(e)

  for (int kt = 0; kt < 16; kt++) {
    __syncthreads();
#pragma unroll
    for (int ss = 0; ss < 2; ss++) {
      int sub = wid * 2 + ss;
      Ks[sub * 64 + lane] = rk[ss];
      Vs[sub * 64 + lane] = rv[ss];
    }
    if (kt < 15) {
      int kt2 = kt + 1;
#pragma unroll
      for (int ss = 0; ss < 2; ss++) {
        int sub = wid * 2 + ss;
        rk[ss] = k8[(size_t)(b * 1024 + kt2 * 64 + (sub >> 1) * 16 + c16) * 64 + hh * 8 + (sub & 1) * 4 + gq];
        rv[ss] = v8[(size_t)(bh * 64 + (sub >> 1) * 16 + c16) * 128 + kt2 * 8 + (sub & 1) * 4 + gq];
      }
    }
    __syncthreads();

    f32x4 sT[4][2] = {};
#pragma unroll
    for (int mf = 0; mf < 4; mf++) {
      short8 ka0 = Ks[(mf * 2 + 0) * 64 + lane];
      short8 ka1 = Ks[(mf * 2 + 1) * 64 + lane];
#pragma unroll
      for (int nf = 0; nf < 2; nf++) {
        sT[mf][nf] = MFMA_BF16(ka0, qf[nf][0], sT[mf][nf]);
        sT[mf][nf] = MFMA_BF16(ka1, qf[nf][1], sT[mf][nf]);
      }
    }

#pragma unroll
    for (int nf = 0; nf < 2; nf++) {
      float pv[4][4];
      float tm = -1e30f;
#pragma unroll
      for (int mf = 0; mf < 4; mf++) {
        f32x4 mk = maskv[kt * 16 + mf * 4 + gq];
#pragma unroll
        for (int r = 0; r < 4; r++) {
          float sv = sT[mf][nf][r] * SCL + mk[r];
          pv[mf][r] = sv;
          tm = fmaxf(tm, sv);
        }
      }
      tm = fmaxf(tm, __shfl_xor(tm, 16));
      tm = fmaxf(tm, __shfl_xor(tm, 32));
      if (!__all(tm - mrun[nf] <= 8.0f)) {
        float mn = fmaxf(mrun[nf], tm);
        float fac = exp2f(mrun[nf] - mn);
        mrun[nf] = mn;
        lrun[nf] *= fac;
#pragma unroll
        for (int dmf = 0; dmf < 4; dmf++) accO[dmf][nf] *= fac;
      }
      float ts = 0.0f;
#pragma unroll
      for (int mf = 0; mf < 4; mf++)
#pragma unroll
        for (int r = 0; r < 4; r++) {
          float p = exp2f(pv[mf][r] - mrun[nf]);
          pv[mf][r] = p;
          ts += p;
        }
      ts += __shfl_xor(ts, 16);
      ts += __shfl_xor(ts, 32);
      lrun[nf] += ts;
#pragma unroll
      for (int mf = 0; mf < 4; mf++) {
        unsigned lo = cvt_pk_bf16(pv[mf][0], pv[mf][1]);
        unsigned hi = cvt_pk_bf16(pv[mf][2], pv[mf][3]);
        int kk = mf >> 1;
        int gr = (mf & 1) * 2 + (gq >> 1);
        uint2 t2; t2.x = lo; t2.y = hi;
        Pb[wid * 512 + ((nf * 2 + kk) * 64 + gr * 16 + c16) * 2 + (gq & 1)] = t2;
      }
    }
    __syncthreads();

    const short8* Pb8 = (const short8*)Pb;
#pragma unroll
    for (int nf = 0; nf < 2; nf++) {
      short8 pb0 = Pb8[wid * 256 + (nf * 2 + 0) * 64 + lane];
      short8 pb1 = Pb8[wid * 256 + (nf * 2 + 1) * 64 + lane];
#pragma unroll
      for (int dmf = 0; dmf < 4; dmf++) {
        short8 va0 = Vs[(dmf * 2 + 0) * 64 + lane];
        short8 va1 = Vs[(dmf * 2 + 1) * 64 + lane];
        accO[dmf][nf] = MFMA_BF16(va0, pb0, accO[dmf][nf]);
        accO[dmf][nf] = MFMA_BF16(va1, pb1, accO[dmf][nf]);
      }
    }
  }

#pragma unroll
  for (int nf = 0; nf < 2; nf++) {
    float inv = 1.0f / lrun[nf];
    int row = b * 1024 + qrow0 + nf * 16 + c16;
#pragma unroll
    for (int dmf = 0; dmf < 4; dmf++) {
      us4 w;
#pragma unroll
      for (int r = 0; r < 4; r++) w[r] = f2bf(accO[dmf][nf][r] * inv);
      *(us4*)&o[(size_t)row * 512 + hh * 64 + dmf * 16 + gq * 4] = w;
    }
  }
}

// ---------- final: out[8192,16] = h @ W_out + b_out ----------
__global__ __launch_bounds__(128) void out_kernel(const float* __restrict__ h,
                                                  const float* __restrict__ Wout,
                                                  const float* __restrict__ bout,
                                                  float* __restrict__ out) {
  __shared__ f32x4 hs4[8][128];
  __shared__ f32x4 Ws4[16][129];
  int t = threadIdx.x;
  int rb = blockIdx.x * 8;
  float* hsf = (float*)hs4;
  float* wsf = (float*)Ws4;
  for (int i = t; i < 4096; i += 128) hsf[i] = h[(size_t)rb * 512 + i];
  for (int i = t; i < 8192; i += 128) wsf[(i & 15) * 516 + (i >> 4)] = Wout[i];
  __syncthreads();
  int r = t >> 4, c = t & 15;
  float acc = bout[c];
  for (int k4 = 0; k4 < 128; k4++) {
    f32x4 a = hs4[r][k4];
    f32x4 w = Ws4[c][k4];
    acc += a[0]*w[0] + a[1]*w[1] + a[2]*w[2] + a[3]*w[3];
  }
  out[(rb + r) * 16 + c] = acc;
}

extern "C" void kernel_launch(void* const* d_in, const int* in_sizes, int n_in,
                              void* d_out, int out_size, void* d_ws, size_t ws_size,
                              hipStream_t stream) {
  const float* x    = (const float*)d_in[0];
  const int*   tmsk = (const int*)d_in[1];
  const float* Win  = (const float*)d_in[2];
  const float* bin  = (const float*)d_in[3];
  const float* ln1g = (const float*)d_in[4];
  const float* ln1b = (const float*)d_in[5];
  const float* Wq   = (const float*)d_in[6];
  const float* Wk   = (const float*)d_in[7];
  const float* Wv   = (const float*)d_in[8];
  const float* Wo   = (const float*)d_in[9];
  const float* ln2g = (const float*)d_in[10];
  const float* ln2b = (const float*)d_in[11];
  const float* W1   = (const float*)d_in[12];
  const float* W2   = (const float*)d_in[13];
  const float* W3   = (const float*)d_in[14];
  const float* Wout = (const float*)d_in[15];
  const float* bout = (const float*)d_in[16];
  float* outp = (float*)d_out;

  char* ws = (char*)d_ws;
  unsigned short* wtq = (unsigned short*)(ws + 0);
  unsigned short* wtk = (unsigned short*)(ws + 6291456);
  unsigned short* wtv = (unsigned short*)(ws + 12582912);
  unsigned short* wto = (unsigned short*)(ws + 18874368);
  unsigned short* wt1 = (unsigned short*)(ws + 25165824);
  unsigned short* wt2 = (unsigned short*)(ws + 50331648);
  unsigned short* wt3 = (unsigned short*)(ws + 75497472);
  float*          h   = (float*)(ws + 100663296);
  unsigned short* xn  = (unsigned short*)(ws + 117440512);
  unsigned short* qb  = (unsigned short*)(ws + 125829120);
  unsigned short* kb  = (unsigned short*)(ws + 134217728);
  unsigned short* vtb = (unsigned short*)(ws + 150994944);
  unsigned short* ob  = (unsigned short*)(ws + 159383552);
  unsigned short* gb  = (unsigned short*)(ws + 167772160);

  dim3 tb(32, 8);
  wtrans_kernel<<<dim3(16, 16, 12), tb, 0, stream>>>(Wq, wtq, 512, 512);
  wtrans_kernel<<<dim3(16, 16, 12), tb, 0, stream>>>(Wk, wtk, 512, 512);
  wtrans_kernel<<<dim3(16, 16, 12), tb, 0, stream>>>(Wv, wtv, 512, 512);
  wtrans_kernel<<<dim3(16, 16, 12), tb, 0, stream>>>(Wo, wto, 512, 512);
  wtrans_kernel<<<dim3(64, 16, 12), tb, 0, stream>>>(W1, wt1, 512, 2048);
  wtrans_kernel<<<dim3(64, 16, 12), tb, 0, stream>>>(W2, wt2, 512, 2048);
  wtrans_kernel<<<dim3(16, 64, 12), tb, 0, stream>>>(W3, wt3, 2048, 512);

  embed_kernel<<<8192, 128, 0, stream>>>(x, Win, bin, h);

  for (int l = 0; l < 12; l++) {
    ln_kernel<<<2048, 256, 0, stream>>>(h, ln1g + l * 512, ln1b + l * 512, xn);
    qkv_gemm<<<dim3(12, 32), 512, 0, stream>>>(xn,
        wtq + (size_t)l * 262144, wtk + (size_t)l * 262144, wtv + (size_t)l * 262144,
        qb, kb, vtb);
    attn_kernel<<<512, 256, 0, stream>>>(qb, kb, vtb, tmsk, ob);
    gemm_res<<<dim3(8, 64), 256, 0, stream>>>(ob, wto + (size_t)l * 262144, h, 64, 8);
    ln_kernel<<<2048, 256, 0, stream>>>(h, ln2g + l * 512, ln2b + l * 512, xn);
    ffn_gemm<<<dim3(16, 32), 512, 0, stream>>>(xn,
        wt1 + (size_t)l * 1048576, wt2 + (size_t)l * 1048576, gb);
    gemm_res<<<dim3(8, 64), 256, 0, stream>>>(gb, wt3 + (size_t)l * 1048576, h, 256, 32);
  }
  out_kernel<<<1024, 128, 0, stream>>>(h, Wout, bout, outp);

  (void)in_sizes; (void)n_in; (void)out_size; (void)ws_size;
}

// Round 14
// 2251.047 us; speedup vs baseline: 1.3059x; 1.0840x over previous
//
#include <hip/hip_runtime.h>

typedef __attribute__((ext_vector_type(8))) short short8;
typedef __attribute__((ext_vector_type(4))) float f32x4;
typedef __attribute__((ext_vector_type(4))) unsigned short us4;

#define MFMA_BF16(a,b,c) __builtin_amdgcn_mfma_f32_16x16x32_bf16((a),(b),(c),0,0,0)

__device__ __forceinline__ unsigned short f2bf(float f) {
  unsigned int u = __float_as_uint(f);
  u += 0x7fffu + ((u >> 16) & 1u);   // round-to-nearest-even
  return (unsigned short)(u >> 16);
}

// pack two f32 -> two bf16 in one instruction
__device__ __forceinline__ unsigned cvt_pk_bf16(float lo, float hi) {
  unsigned r;
  asm("v_cvt_pk_bf16_f32 %0, %1, %2" : "=v"(r) : "v"(lo), "v"(hi));
  return r;
}

// bijective XCD-chunk swizzle (attention only)
__device__ __forceinline__ int xcd_swz(int lid, int nwg) {
  return (lid & 7) * (nwg >> 3) + (lid >> 3);
}

// ---------- weight transpose + f32->bf16: src f32 [R][C] -> dst bf16 [C][R], batched over z ----------
__global__ __launch_bounds__(256) void wtrans_kernel(const float* __restrict__ src,
                                                     unsigned short* __restrict__ dst,
                                                     int R, int C) {
  __shared__ float tile[32][33];
  int c0 = blockIdx.x * 32, r0 = blockIdx.y * 32;
  const float* s = src + (size_t)blockIdx.z * R * C;
  unsigned short* d = dst + (size_t)blockIdx.z * R * C;
  int tx = threadIdx.x, ty = threadIdx.y;
#pragma unroll
  for (int i = 0; i < 32; i += 8)
    tile[ty + i][tx] = s[(size_t)(r0 + ty + i) * C + c0 + tx];
  __syncthreads();
#pragma unroll
  for (int i = 0; i < 32; i += 8)
    d[(size_t)(c0 + ty + i) * R + r0 + tx] = f2bf(tile[tx][ty + i]);
}

// ---------- embed: h = x @ W_in + b_in + pos_emb ----------
__global__ __launch_bounds__(128) void embed_kernel(const float* __restrict__ x,
                                                    const float* __restrict__ Win,
                                                    const float* __restrict__ bin,
                                                    float* __restrict__ h) {
  __shared__ float xs[16];
  int m = blockIdx.x, t = threadIdx.x;
  if (t < 16) xs[t] = x[m * 16 + t];
  __syncthreads();
  int l = m & 1023, hi = l >> 5, wi = l & 31;
#pragma unroll
  for (int e0 = 0; e0 < 512; e0 += 128) {
    int e = e0 + t;
    float a = bin[e];
#pragma unroll
    for (int kk = 0; kk < 16; kk++) a += xs[kk] * Win[kk * 512 + e];
    int j = e & 255;
    float p = (e < 256) ? (float)hi : (float)wi;
    float inv = expf((float)j * (-9.210340371976184f / 256.0f));  // 10000^(-j/256)
    a += cosf(p * inv);
    h[(size_t)m * 512 + e] = a;
  }
}

// ---------- layernorm, wave-per-row (no LDS, no barriers): 4 rows/block ----------
__global__ __launch_bounds__(256) void ln_kernel(const float* __restrict__ h,
                                                 const float* __restrict__ gw,
                                                 const float* __restrict__ bw,
                                                 unsigned short* __restrict__ xn) {
  int row = blockIdx.x * 4 + (threadIdx.x >> 6);
  int lane = threadIdx.x & 63;
  const f32x4* hr = (const f32x4*)&h[(size_t)row * 512];
  f32x4 v0 = hr[lane], v1 = hr[lane + 64];
  float s = v0[0]+v0[1]+v0[2]+v0[3] + v1[0]+v1[1]+v1[2]+v1[3];
  float q = v0[0]*v0[0]+v0[1]*v0[1]+v0[2]*v0[2]+v0[3]*v0[3]
          + v1[0]*v1[0]+v1[1]*v1[1]+v1[2]*v1[2]+v1[3]*v1[3];
#pragma unroll
  for (int o = 1; o < 64; o <<= 1) { s += __shfl_xor(s, o); q += __shfl_xor(q, o); }
  float mean = s * (1.0f / 512.0f);
  float var = q * (1.0f / 512.0f) - mean * mean;
  float rstd = rsqrtf(var + 1e-5f);
  f32x4 g0 = ((const f32x4*)gw)[lane], g1 = ((const f32x4*)gw)[lane + 64];
  f32x4 b0 = ((const f32x4*)bw)[lane], b1 = ((const f32x4*)bw)[lane + 64];
  us4 w0, w1;
#pragma unroll
  for (int r = 0; r < 4; r++) {
    w0[r] = f2bf((v0[r] - mean) * rstd * g0[r] + b0[r]);
    w1[r] = f2bf((v1[r] - mean) * rstd * g1[r] + b1[r]);
  }
  *(us4*)&xn[(size_t)row * 512 + lane * 4] = w0;
  *(us4*)&xn[(size_t)row * 512 + 256 + lane * 4] = w1;
}

// ---------- QKV GEMM (reg-staged BK=64, BM=256, 8 waves): V written directly transposed ----------
__global__ __launch_bounds__(512) void qkv_gemm(const unsigned short* __restrict__ xn,
                                                const unsigned short* __restrict__ wtq,
                                                const unsigned short* __restrict__ wtk,
                                                const unsigned short* __restrict__ wtv,
                                                unsigned short* __restrict__ qo,
                                                unsigned short* __restrict__ ko,
                                                unsigned short* __restrict__ vt) {
  __shared__ short8 As[2048];   // 32 subtiles (rg*2+kc), 16x32 fragment-linear
  __shared__ short8 Bs[1024];   // 16 subtiles
  int n0 = blockIdx.x * 128, m0 = blockIdx.y * 256;
  int sel = n0 >> 9;
  const short8* wt = (const short8*)(sel == 0 ? wtq : sel == 1 ? wtk : wtv);
  int nw = n0 & 511;
  const short8* A8 = (const short8*)xn;
  int tid = threadIdx.x, wid = tid >> 6, lane = tid & 63;
  int wr = wid >> 1, wc = wid & 1, c16 = lane & 15, g = lane >> 4;
  const short8* aSrc[4];
  const short8* bSrc[2];
#pragma unroll
  for (int s = 0; s < 4; s++) {
    int sub = wid * 4 + s, rg = sub >> 1, kc = sub & 1;
    aSrc[s] = A8 + (size_t)(m0 + rg * 16 + c16) * 64 + kc * 4 + g;
  }
#pragma unroll
  for (int s = 0; s < 2; s++) {
    int sub = wid * 2 + s, rg = sub >> 1, kc = sub & 1;
    bSrc[s] = wt + (size_t)(nw + rg * 16 + c16) * 64 + kc * 4 + g;
  }
  f32x4 acc[4][4] = {};
  short8 ra[4], rb[2];
#pragma unroll
  for (int s = 0; s < 4; s++) ra[s] = aSrc[s][0];
#pragma unroll
  for (int s = 0; s < 2; s++) rb[s] = bSrc[s][0];
  for (int kt = 0; kt < 8; kt++) {
    __syncthreads();
#pragma unroll
    for (int s = 0; s < 4; s++) As[(wid * 4 + s) * 64 + lane] = ra[s];
#pragma unroll
    for (int s = 0; s < 2; s++) Bs[(wid * 2 + s) * 64 + lane] = rb[s];
    if (kt < 7) {
#pragma unroll
      for (int s = 0; s < 4; s++) ra[s] = aSrc[s][(kt + 1) * 8];
#pragma unroll
      for (int s = 0; s < 2; s++) rb[s] = bSrc[s][(kt + 1) * 8];
    }
    __syncthreads();
#pragma unroll
    for (int kc = 0; kc < 2; kc++) {
      short8 af[4], bf[4];
#pragma unroll
      for (int mf = 0; mf < 4; mf++) af[mf] = As[((wr * 4 + mf) * 2 + kc) * 64 + lane];
#pragma unroll
      for (int nf = 0; nf < 4; nf++) bf[nf] = Bs[((wc * 4 + nf) * 2 + kc) * 64 + lane];
#pragma unroll
      for (int mf = 0; mf < 4; mf++)
#pragma unroll
        for (int nf = 0; nf < 4; nf++)
          acc[mf][nf] = MFMA_BF16(af[mf], bf[nf], acc[mf][nf]);
    }
  }
  if (sel < 2) {
    unsigned short* out = sel == 0 ? qo : ko;
#pragma unroll
    for (int mf = 0; mf < 4; mf++)
#pragma unroll
      for (int nf = 0; nf < 4; nf++) {
        int col = nw + wc * 64 + nf * 16 + c16;
#pragma unroll
        for (int r = 0; r < 4; r++) {
          int row = m0 + wr * 64 + mf * 16 + g * 4 + r;
          out[(size_t)row * 512 + col] = f2bf(acc[mf][nf][r]);
        }
      }
  } else {
    // write V transposed: vt[(b*8+h)*64 + d][l] with l-contiguous 8B stores
    int b8 = (m0 >> 10) * 8;
    int loff = (m0 & 1023) + wr * 64;
#pragma unroll
    for (int mf = 0; mf < 4; mf++)
#pragma unroll
      for (int nf = 0; nf < 4; nf++) {
        int c = nw + wc * 64 + nf * 16 + c16;
        int bh = b8 + (c >> 6), d = c & 63;
        us4 w;
#pragma unroll
        for (int r = 0; r < 4; r++) w[r] = f2bf(acc[mf][nf][r]);
        *(us4*)&vt[(size_t)(bh * 64 + d) * 1024 + loff + mf * 16 + g * 4] = w;
      }
  }
}

// ---------- residual GEMM: h += A(bf16)[8192,K] @ W, BM=128 BN=128, 8 waves (2x4) ----------
// grid (4, 64) = 256 blocks of 512 threads; per wave 2A+2B loads / 16 MFMA per K-step.
__global__ __launch_bounds__(512) void gemm_res(const unsigned short* __restrict__ A,
                                                const unsigned short* __restrict__ Wt,
                                                float* __restrict__ h, int Kd8, int nkt64) {
  __shared__ short8 As[1024];   // 16 subtiles
  __shared__ short8 Bs[1024];   // 16 subtiles
  int n0 = blockIdx.x * 128, m0 = blockIdx.y * 128;
  const short8* A8 = (const short8*)A;
  const short8* W8 = (const short8*)Wt;
  int tid = threadIdx.x, wid = tid >> 6, lane = tid & 63;
  int wr = wid >> 2, wc = wid & 3, c16 = lane & 15, g = lane >> 4;
  const short8* aSrc[2];
  const short8* bSrc[2];
#pragma unroll
  for (int s = 0; s < 2; s++) {
    int sub = wid * 2 + s, rg = sub >> 1, kc = sub & 1;
    aSrc[s] = A8 + (size_t)(m0 + rg * 16 + c16) * Kd8 + kc * 4 + g;
    bSrc[s] = W8 + (size_t)(n0 + rg * 16 + c16) * Kd8 + kc * 4 + g;
  }
  f32x4 acc[4][2] = {};
  short8 ra[2], rb[2];
#pragma unroll
  for (int s = 0; s < 2; s++) { ra[s] = aSrc[s][0]; rb[s] = bSrc[s][0]; }
  for (int kt = 0; kt < nkt64; kt++) {
    __syncthreads();
#pragma unroll
    for (int s = 0; s < 2; s++) {
      As[(wid * 2 + s) * 64 + lane] = ra[s];
      Bs[(wid * 2 + s) * 64 + lane] = rb[s];
    }
    if (kt + 1 < nkt64) {
#pragma unroll
      for (int s = 0; s < 2; s++) {
        ra[s] = aSrc[s][(kt + 1) * 8];
        rb[s] = bSrc[s][(kt + 1) * 8];
      }
    }
    __syncthreads();
#pragma unroll
    for (int kc = 0; kc < 2; kc++) {
      short8 af[4], bf[2];
#pragma unroll
      for (int mf = 0; mf < 4; mf++) af[mf] = As[((wr * 4 + mf) * 2 + kc) * 64 + lane];
#pragma unroll
      for (int nf = 0; nf < 2; nf++) bf[nf] = Bs[((wc * 2 + nf) * 2 + kc) * 64 + lane];
#pragma unroll
      for (int mf = 0; mf < 4; mf++)
#pragma unroll
        for (int nf = 0; nf < 2; nf++)
          acc[mf][nf] = MFMA_BF16(af[mf], bf[nf], acc[mf][nf]);
    }
  }
#pragma unroll
  for (int mf = 0; mf < 4; mf++)
#pragma unroll
    for (int nf = 0; nf < 2; nf++) {
      int col = n0 + wc * 32 + nf * 16 + c16;
#pragma unroll
      for (int r = 0; r < 4; r++) {
        int row = m0 + wr * 64 + mf * 16 + g * 4 + r;
        h[(size_t)row * 512 + col] += acc[mf][nf][r];
      }
    }
}

// ---------- FFN fused dual GEMM, reg-staged BK=64, BM=256, 8 waves ----------
__global__ __launch_bounds__(512) void ffn_gemm(const unsigned short* __restrict__ xn,
                                                const unsigned short* __restrict__ w1t,
                                                const unsigned short* __restrict__ w2t,
                                                unsigned short* __restrict__ gout) {
  __shared__ short8 As[2048];    // 32 subtiles
  __shared__ short8 B1s[1024];   // 16 subtiles
  __shared__ short8 B2s[1024];
  int n0 = blockIdx.x * 128, m0 = blockIdx.y * 256;
  const short8* A8 = (const short8*)xn;
  const short8* W18 = (const short8*)w1t;
  const short8* W28 = (const short8*)w2t;
  int tid = threadIdx.x, wid = tid >> 6, lane = tid & 63;
  int wr = wid >> 1, wc = wid & 1, c16 = lane & 15, g = lane >> 4;
  const short8* aSrc[4];
  const short8* b1Src[2];
  const short8* b2Src[2];
#pragma unroll
  for (int s = 0; s < 4; s++) {
    int sub = wid * 4 + s, rg = sub >> 1, kc = sub & 1;
    aSrc[s] = A8 + (size_t)(m0 + rg * 16 + c16) * 64 + kc * 4 + g;
  }
#pragma unroll
  for (int s = 0; s < 2; s++) {
    int sub = wid * 2 + s, rg = sub >> 1, kc = sub & 1;
    b1Src[s] = W18 + (size_t)(n0 + rg * 16 + c16) * 64 + kc * 4 + g;
    b2Src[s] = W28 + (size_t)(n0 + rg * 16 + c16) * 64 + kc * 4 + g;
  }
  f32x4 acc1[4][4] = {};
  f32x4 acc2[4][4] = {};
  short8 ra[4], rb1[2], rb2[2];
#pragma unroll
  for (int s = 0; s < 4; s++) ra[s] = aSrc[s][0];
#pragma unroll
  for (int s = 0; s < 2; s++) { rb1[s] = b1Src[s][0]; rb2[s] = b2Src[s][0]; }
  for (int kt = 0; kt < 8; kt++) {
    __syncthreads();
#pragma unroll
    for (int s = 0; s < 4; s++) As[(wid * 4 + s) * 64 + lane] = ra[s];
#pragma unroll
    for (int s = 0; s < 2; s++) {
      B1s[(wid * 2 + s) * 64 + lane] = rb1[s];
      B2s[(wid * 2 + s) * 64 + lane] = rb2[s];
    }
    if (kt < 7) {
#pragma unroll
      for (int s = 0; s < 4; s++) ra[s] = aSrc[s][(kt + 1) * 8];
#pragma unroll
      for (int s = 0; s < 2; s++) {
        rb1[s] = b1Src[s][(kt + 1) * 8];
        rb2[s] = b2Src[s][(kt + 1) * 8];
      }
    }
    __syncthreads();
#pragma unroll
    for (int kc = 0; kc < 2; kc++) {
      short8 af[4], b1f[4], b2f[4];
#pragma unroll
      for (int mf = 0; mf < 4; mf++) af[mf] = As[((wr * 4 + mf) * 2 + kc) * 64 + lane];
#pragma unroll
      for (int nf = 0; nf < 4; nf++) {
        b1f[nf] = B1s[((wc * 4 + nf) * 2 + kc) * 64 + lane];
        b2f[nf] = B2s[((wc * 4 + nf) * 2 + kc) * 64 + lane];
      }
#pragma unroll
      for (int mf = 0; mf < 4; mf++)
#pragma unroll
        for (int nf = 0; nf < 4; nf++) {
          acc1[mf][nf] = MFMA_BF16(af[mf], b1f[nf], acc1[mf][nf]);
          acc2[mf][nf] = MFMA_BF16(af[mf], b2f[nf], acc2[mf][nf]);
        }
    }
  }
#pragma unroll
  for (int mf = 0; mf < 4; mf++)
#pragma unroll
    for (int nf = 0; nf < 4; nf++) {
      int col = n0 + wc * 64 + nf * 16 + c16;
#pragma unroll
      for (int r = 0; r < 4; r++) {
        int row = m0 + wr * 64 + mf * 16 + g * 4 + r;
        float xx = acc1[mf][nf][r];
        float yy = acc2[mf][nf][r];
        float sg = xx / (1.0f + __expf(-xx));
        gout[(size_t)row * 2048 + col] = f2bf(sg * yy);
      }
    }
}

// ---------- flash attention: log2-domain softmax + defer-rescale + cvt_pk P-pack ----------
__global__ __launch_bounds__(256) void attn_kernel(const unsigned short* __restrict__ q,
                                                   const unsigned short* __restrict__ k,
                                                   const unsigned short* __restrict__ vt,
                                                   const int* __restrict__ tmsk,
                                                   unsigned short* __restrict__ o) {
  __shared__ short8 Ks[512];
  __shared__ short8 Vs[512];
  __shared__ uint2  Pb[2048];
  __shared__ f32x4  maskv[256];

  int s = xcd_swz((int)blockIdx.x, 512);
  int qb = s & 7;
  int bh = s >> 3;
  int b = bh >> 3, hh = bh & 7;
  int tid = threadIdx.x, wid = tid >> 6, lane = tid & 63;
  int c16 = lane & 15, gq = lane >> 4;
  int qrow0 = qb * 128 + wid * 32;

  const short8* q8 = (const short8*)q;
  const short8* k8 = (const short8*)k;
  const short8* v8 = (const short8*)vt;

  short8 qf[2][2];
#pragma unroll
  for (int nf = 0; nf < 2; nf++)
#pragma unroll
    for (int dc = 0; dc < 2; dc++)
      qf[nf][dc] = q8[(size_t)(b * 1024 + qrow0 + nf * 16 + c16) * 64 + hh * 8 + dc * 4 + gq];

  {
    int4 mm = ((const int4*)(tmsk + b * 1024))[tid];
    f32x4 ma;
    ma[0] = (mm.x == 0) ? -1.442695e9f : 0.0f;
    ma[1] = (mm.y == 0) ? -1.442695e9f : 0.0f;
    ma[2] = (mm.z == 0) ? -1.442695e9f : 0.0f;
    ma[3] = (mm.w == 0) ? -1.442695e9f : 0.0f;
    maskv[tid] = ma;
  }

  short8 rk[2], rv[2];
#pragma unroll
  for (int ss = 0; ss < 2; ss++) {
    int sub = wid * 2 + ss;
    rk[ss] = k8[(size_t)(b * 1024 + (sub >> 1) * 16 + c16) * 64 + hh * 8 + (sub & 1) * 4 + gq];
    rv[ss] = v8[(size_t)(bh * 64 + (sub >> 1) * 16 + c16) * 128 + (sub & 1) * 4 + gq];
  }

  float mrun[2] = {-1e30f, -1e30f};
  float lrun[2] = {0.0f, 0.0f};
  f32x4 accO[4][2] = {};
  const float SCL = 0.125f * 1.4426950408889634f;  // scale * log2(e)

  for (int kt = 0; kt < 16; kt++) {
    __syncthreads();
#pragma unroll
    for (int ss = 0; ss < 2; ss++) {
      int sub = wid * 2 + ss;
      Ks[sub * 64 + lane] = rk[ss];
      Vs[sub * 64 + lane] = rv[ss];
    }
    if (kt < 15) {
      int kt2 = kt + 1;
#pragma unroll
      for (int ss = 0; ss < 2; ss++) {
        int sub = wid * 2 + ss;
        rk[ss] = k8[(size_t)(b * 1024 + kt2 * 64 + (sub >> 1) * 16 + c16) * 64 + hh * 8 + (sub & 1) * 4 + gq];
        rv[ss] = v8[(size_t)(bh * 64 + (sub >> 1) * 16 + c16) * 128 + kt2 * 8 + (sub & 1) * 4 + gq];
      }
    }
    __syncthreads();

    f32x4 sT[4][2] = {};
#pragma unroll
    for (int mf = 0; mf < 4; mf++) {
      short8 ka0 = Ks[(mf * 2 + 0) * 64 + lane];
      short8 ka1 = Ks[(mf * 2 + 1) * 64 + lane];
#pragma unroll
      for (int nf = 0; nf < 2; nf++) {
        sT[mf][nf] = MFMA_BF16(ka0, qf[nf][0], sT[mf][nf]);
        sT[mf][nf] = MFMA_BF16(ka1, qf[nf][1], sT[mf][nf]);
      }
    }

#pragma unroll
    for (int nf = 0; nf < 2; nf++) {
      float pv[4][4];
      float tm = -1e30f;
#pragma unroll
      for (int mf = 0; mf < 4; mf++) {
        f32x4 mk = maskv[kt * 16 + mf * 4 + gq];
#pragma unroll
        for (int r = 0; r < 4; r++) {
          float sv = sT[mf][nf][r] * SCL + mk[r];
          pv[mf][r] = sv;
          tm = fmaxf(tm, sv);
        }
      }
      tm = fmaxf(tm, __shfl_xor(tm, 16));
      tm = fmaxf(tm, __shfl_xor(tm, 32));
      if (!__all(tm - mrun[nf] <= 8.0f)) {
        float mn = fmaxf(mrun[nf], tm);
        float fac = exp2f(mrun[nf] - mn);
        mrun[nf] = mn;
        lrun[nf] *= fac;
#pragma unroll
        for (int dmf = 0; dmf < 4; dmf++) accO[dmf][nf] *= fac;
      }
      float ts = 0.0f;
#pragma unroll
      for (int mf = 0; mf < 4; mf++)
#pragma unroll
        for (int r = 0; r < 4; r++) {
          float p = exp2f(pv[mf][r] - mrun[nf]);
          pv[mf][r] = p;
          ts += p;
        }
      ts += __shfl_xor(ts, 16);
      ts += __shfl_xor(ts, 32);
      lrun[nf] += ts;
#pragma unroll
      for (int mf = 0; mf < 4; mf++) {
        unsigned lo = cvt_pk_bf16(pv[mf][0], pv[mf][1]);
        unsigned hi = cvt_pk_bf16(pv[mf][2], pv[mf][3]);
        int kk = mf >> 1;
        int gr = (mf & 1) * 2 + (gq >> 1);
        uint2 t2; t2.x = lo; t2.y = hi;
        Pb[wid * 512 + ((nf * 2 + kk) * 64 + gr * 16 + c16) * 2 + (gq & 1)] = t2;
      }
    }
    __syncthreads();

    const short8* Pb8 = (const short8*)Pb;
#pragma unroll
    for (int nf = 0; nf < 2; nf++) {
      short8 pb0 = Pb8[wid * 256 + (nf * 2 + 0) * 64 + lane];
      short8 pb1 = Pb8[wid * 256 + (nf * 2 + 1) * 64 + lane];
#pragma unroll
      for (int dmf = 0; dmf < 4; dmf++) {
        short8 va0 = Vs[(dmf * 2 + 0) * 64 + lane];
        short8 va1 = Vs[(dmf * 2 + 1) * 64 + lane];
        accO[dmf][nf] = MFMA_BF16(va0, pb0, accO[dmf][nf]);
        accO[dmf][nf] = MFMA_BF16(va1, pb1, accO[dmf][nf]);
      }
    }
  }

#pragma unroll
  for (int nf = 0; nf < 2; nf++) {
    float inv = 1.0f / lrun[nf];
    int row = b * 1024 + qrow0 + nf * 16 + c16;
#pragma unroll
    for (int dmf = 0; dmf < 4; dmf++) {
      us4 w;
#pragma unroll
      for (int r = 0; r < 4; r++) w[r] = f2bf(accO[dmf][nf][r] * inv);
      *(us4*)&o[(size_t)row * 512 + hh * 64 + dmf * 16 + gq * 4] = w;
    }
  }
}

// ---------- final: out[8192,16] = h @ W_out + b_out ----------
__global__ __launch_bounds__(128) void out_kernel(const float* __restrict__ h,
                                                  const float* __restrict__ Wout,
                                                  const float* __restrict__ bout,
                                                  float* __restrict__ out) {
  __shared__ f32x4 hs4[8][128];
  __shared__ f32x4 Ws4[16][129];
  int t = threadIdx.x;
  int rb = blockIdx.x * 8;
  float* hsf = (float*)hs4;
  float* wsf = (float*)Ws4;
  for (int i = t; i < 4096; i += 128) hsf[i] = h[(size_t)rb * 512 + i];
  for (int i = t; i < 8192; i += 128) wsf[(i & 15) * 516 + (i >> 4)] = Wout[i];
  __syncthreads();
  int r = t >> 4, c = t & 15;
  float acc = bout[c];
  for (int k4 = 0; k4 < 128; k4++) {
    f32x4 a = hs4[r][k4];
    f32x4 w = Ws4[c][k4];
    acc += a[0]*w[0] + a[1]*w[1] + a[2]*w[2] + a[3]*w[3];
  }
  out[(rb + r) * 16 + c] = acc;
}

extern "C" void kernel_launch(void* const* d_in, const int* in_sizes, int n_in,
                              void* d_out, int out_size, void* d_ws, size_t ws_size,
                              hipStream_t stream) {
  const float* x    = (const float*)d_in[0];
  const int*   tmsk = (const int*)d_in[1];
  const float* Win  = (const float*)d_in[2];
  const float* bin  = (const float*)d_in[3];
  const float* ln1g = (const float*)d_in[4];
  const float* ln1b = (const float*)d_in[5];
  const float* Wq   = (const float*)d_in[6];
  const float* Wk   = (const float*)d_in[7];
  const float* Wv   = (const float*)d_in[8];
  const float* Wo   = (const float*)d_in[9];
  const float* ln2g = (const float*)d_in[10];
  const float* ln2b = (const float*)d_in[11];
  const float* W1   = (const float*)d_in[12];
  const float* W2   = (const float*)d_in[13];
  const float* W3   = (const float*)d_in[14];
  const float* Wout = (const float*)d_in[15];
  const float* bout = (const float*)d_in[16];
  float* outp = (float*)d_out;

  char* ws = (char*)d_ws;
  unsigned short* wtq = (unsigned short*)(ws + 0);
  unsigned short* wtk = (unsigned short*)(ws + 6291456);
  unsigned short* wtv = (unsigned short*)(ws + 12582912);
  unsigned short* wto = (unsigned short*)(ws + 18874368);
  unsigned short* wt1 = (unsigned short*)(ws + 25165824);
  unsigned short* wt2 = (unsigned short*)(ws + 50331648);
  unsigned short* wt3 = (unsigned short*)(ws + 75497472);
  float*          h   = (float*)(ws + 100663296);
  unsigned short* xn  = (unsigned short*)(ws + 117440512);
  unsigned short* qb  = (unsigned short*)(ws + 125829120);
  unsigned short* kb  = (unsigned short*)(ws + 134217728);
  unsigned short* vtb = (unsigned short*)(ws + 150994944);
  unsigned short* ob  = (unsigned short*)(ws + 159383552);
  unsigned short* gb  = (unsigned short*)(ws + 167772160);

  dim3 tb(32, 8);
  wtrans_kernel<<<dim3(16, 16, 12), tb, 0, stream>>>(Wq, wtq, 512, 512);
  wtrans_kernel<<<dim3(16, 16, 12), tb, 0, stream>>>(Wk, wtk, 512, 512);
  wtrans_kernel<<<dim3(16, 16, 12), tb, 0, stream>>>(Wv, wtv, 512, 512);
  wtrans_kernel<<<dim3(16, 16, 12), tb, 0, stream>>>(Wo, wto, 512, 512);
  wtrans_kernel<<<dim3(64, 16, 12), tb, 0, stream>>>(W1, wt1, 512, 2048);
  wtrans_kernel<<<dim3(64, 16, 12), tb, 0, stream>>>(W2, wt2, 512, 2048);
  wtrans_kernel<<<dim3(16, 64, 12), tb, 0, stream>>>(W3, wt3, 2048, 512);

  embed_kernel<<<8192, 128, 0, stream>>>(x, Win, bin, h);

  for (int l = 0; l < 12; l++) {
    ln_kernel<<<2048, 256, 0, stream>>>(h, ln1g + l * 512, ln1b + l * 512, xn);
    qkv_gemm<<<dim3(12, 32), 512, 0, stream>>>(xn,
        wtq + (size_t)l * 262144, wtk + (size_t)l * 262144, wtv + (size_t)l * 262144,
        qb, kb, vtb);
    attn_kernel<<<512, 256, 0, stream>>>(qb, kb, vtb, tmsk, ob);
    gemm_res<<<dim3(4, 64), 512, 0, stream>>>(ob, wto + (size_t)l * 262144, h, 64, 8);
    ln_kernel<<<2048, 256, 0, stream>>>(h, ln2g + l * 512, ln2b + l * 512, xn);
    ffn_gemm<<<dim3(16, 32), 512, 0, stream>>>(xn,
        wt1 + (size_t)l * 1048576, wt2 + (size_t)l * 1048576, gb);
    gemm_res<<<dim3(4, 64), 512, 0, stream>>>(gb, wt3 + (size_t)l * 1048576, h, 256, 32);
  }
  out_kernel<<<1024, 128, 0, stream>>>(h, Wout, bout, outp);

  (void)in_sizes; (void)n_in; (void)out_size; (void)ws_size;
}